// Round 3
// baseline (1248.036 us; speedup 1.0000x reference)
//
#include <hip/hip_runtime.h>
#include <hip/hip_bf16.h>

#define D128 128

typedef __attribute__((ext_vector_type(8))) short bf16x8;
typedef __attribute__((ext_vector_type(4))) float f32x4;

__device__ __forceinline__ float b2f(unsigned short u) {
    union { unsigned int i; float f; } z;
    z.i = ((unsigned int)u) << 16;
    return z.f;
}

__device__ __forceinline__ unsigned short f2b(float f) {
    union { float f; unsigned int i; } z;
    z.f = f;
    unsigned int r = z.i + 0x7FFFu + ((z.i >> 16) & 1u);  // round-to-nearest-even
    return (unsigned short)(r >> 16);
}

__device__ __forceinline__ f32x4 mfma16(bf16x8 a, bf16x8 b, f32x4 c) {
    return __builtin_amdgcn_mfma_f32_16x16x32_bf16(a, b, c, 0, 0, 0);
}

// ---------------------------------------------------------------------------
// Kernel 0: convert W1, Wg, W2 (fp32 128x128 each) to bf16 in workspace.
// ---------------------------------------------------------------------------
__global__ void k_cvt(const float* __restrict__ W1,
                      const float* __restrict__ Wg,
                      const float* __restrict__ W2,
                      unsigned short* __restrict__ wbf)
{
    int t = blockIdx.x * blockDim.x + threadIdx.x;  // 12288 threads, 4 elems each
    if (t >= 12288) return;
    const int mat = t / 4096;          // 0,1,2
    const int idx = (t % 4096) * 4;    // element offset within matrix
    const float* src = mat == 0 ? W1 : (mat == 1 ? Wg : W2);
    float4 f = *(const float4*)(src + idx);
    unsigned short* dst = wbf + mat * 16384 + idx;
    dst[0] = f2b(f.x); dst[1] = f2b(f.y); dst[2] = f2b(f.z); dst[3] = f2b(f.w);
}

// ---------------------------------------------------------------------------
// Kernel 1: fused  y1 = leaky(x,0.01) @ W1^T + b1 ;  h = y1 @ Wg^T
// Block = 256 threads (4 waves), 128 rows x 128 cols per block.
// y1 round-trips through LDS as bf16 (padded stride to avoid bank conflicts).
// ---------------------------------------------------------------------------
#define LDST 136  // 128 + 8 bf16 padding

__global__ __launch_bounds__(256) void k_fused_gemm2(
    const float* __restrict__ x,
    const unsigned short* __restrict__ W1b,
    const float* __restrict__ b1,
    const unsigned short* __restrict__ Wgb,
    unsigned short* __restrict__ hfeat, int N)
{
    __shared__ unsigned short ldsY[128 * LDST];
    const int wave = threadIdx.x >> 6;
    const int lane = threadIdx.x & 63;
    const int lmod = lane & 15;
    const int ldiv = lane >> 4;
    const int rowBase = blockIdx.x * 128;
    const int kOff = ldiv * 8;

    // ---- GEMM1: y1 = leaky(x) @ W1^T ----
    f32x4 acc[2][8] = {};
    #pragma unroll
    for (int ks = 0; ks < 4; ++ks) {
        const int kb = ks * 32 + kOff;
        bf16x8 afr[2];
        #pragma unroll
        for (int rt = 0; rt < 2; ++rt) {
            int row = rowBase + wave * 32 + rt * 16 + lmod;
            row = min(row, N - 1);
            const float* px = x + (size_t)row * D128 + kb;
            float4 f0 = *(const float4*)px;
            float4 f1 = *(const float4*)(px + 4);
            float tmp[8] = { f0.x, f0.y, f0.z, f0.w, f1.x, f1.y, f1.z, f1.w };
            union { bf16x8 v; unsigned short s[8]; } o;
            #pragma unroll
            for (int j = 0; j < 8; ++j) {
                float f = tmp[j];
                f = f >= 0.f ? f : 0.01f * f;
                o.s[j] = f2b(f);
            }
            afr[rt] = o.v;
        }
        #pragma unroll
        for (int ct = 0; ct < 8; ++ct) {
            bf16x8 bfr = *(const bf16x8*)(W1b + (size_t)(ct * 16 + lmod) * D128 + kb);
            acc[0][ct] = mfma16(afr[0], bfr, acc[0][ct]);
            acc[1][ct] = mfma16(afr[1], bfr, acc[1][ct]);
        }
    }

    // add b1, cast bf16, park y1 in LDS
    #pragma unroll
    for (int ct = 0; ct < 8; ++ct) {
        const int col = ct * 16 + lmod;
        const float bias = b1[col];
        #pragma unroll
        for (int rt = 0; rt < 2; ++rt)
            #pragma unroll
            for (int r = 0; r < 4; ++r) {
                int rowl = wave * 32 + rt * 16 + ldiv * 4 + r;
                ldsY[rowl * LDST + col] = f2b(acc[rt][ct][r] + bias);
            }
    }
    __syncthreads();

    // ---- GEMM2: h = y1 @ Wg^T ----
    f32x4 acc2[2][8] = {};
    #pragma unroll
    for (int ks = 0; ks < 4; ++ks) {
        const int kb = ks * 32 + kOff;
        bf16x8 afr[2];
        #pragma unroll
        for (int rt = 0; rt < 2; ++rt) {
            int rowl = wave * 32 + rt * 16 + lmod;
            afr[rt] = *(const bf16x8*)&ldsY[rowl * LDST + kb];
        }
        #pragma unroll
        for (int ct = 0; ct < 8; ++ct) {
            bf16x8 bfr = *(const bf16x8*)(Wgb + (size_t)(ct * 16 + lmod) * D128 + kb);
            acc2[0][ct] = mfma16(afr[0], bfr, acc2[0][ct]);
            acc2[1][ct] = mfma16(afr[1], bfr, acc2[1][ct]);
        }
    }

    // store h (bf16) to workspace
    #pragma unroll
    for (int ct = 0; ct < 8; ++ct) {
        const int col = ct * 16 + lmod;
        #pragma unroll
        for (int rt = 0; rt < 2; ++rt)
            #pragma unroll
            for (int r = 0; r < 4; ++r) {
                int row = rowBase + wave * 32 + rt * 16 + ldiv * 4 + r;
                if (row < N) hfeat[(size_t)row * D128 + col] = f2b(acc2[rt][ct][r]);
            }
    }
}

// ---------------------------------------------------------------------------
// Kernel 2: a_src[n,h] = sum_c h[n,h,c]*att_src[h,c];  same for a_dst
// one thread per (node, head). att vectors are fp32.
// ---------------------------------------------------------------------------
__global__ void k_att(const unsigned short* __restrict__ hfeat,
                      const float* __restrict__ att_s,
                      const float* __restrict__ att_d,
                      float* __restrict__ asrc, float* __restrict__ adst, int N)
{
    int t = blockIdx.x * blockDim.x + threadIdx.x;
    if (t >= N * 4) return;
    const int node = t >> 2, head = t & 3;
    const unsigned short* p  = hfeat + (size_t)node * D128 + head * 32;
    const float* ps = att_s + head * 32;
    const float* pd = att_d + head * 32;
    float s = 0.f, d = 0.f;
    #pragma unroll
    for (int j0 = 0; j0 < 32; j0 += 8) {
        union { uint4 q; unsigned short s[8]; } u;
        u.q = *(const uint4*)(p + j0);
        #pragma unroll
        for (int j = 0; j < 8; ++j) {
            float f = b2f(u.s[j]);
            s += f * ps[j0 + j];
            d += f * pd[j0 + j];
        }
    }
    asrc[t] = s;
    adst[t] = d;
}

// ---------------------------------------------------------------------------
// Kernel 3: denom[d,h] += exp(leaky(a_src[s,h]+a_dst[d,h], 0.2))
// Skipping segment_max is exact math for the softmax ratio; |alpha| is small
// so fp32 exp cannot overflow.
// ---------------------------------------------------------------------------
__global__ void k_denom(const int* __restrict__ ei,
                        const float* __restrict__ asrc,
                        const float* __restrict__ adst,
                        float* __restrict__ denom, int E)
{
    int e = blockIdx.x * blockDim.x + threadIdx.x;
    if (e >= E) return;
    const int s = ei[e], d = ei[E + e];
    const float4 as = *(const float4*)(asrc + (size_t)s * 4);
    const float4 ad = *(const float4*)(adst + (size_t)d * 4);
    float a0 = as.x + ad.x, a1 = as.y + ad.y, a2 = as.z + ad.z, a3 = as.w + ad.w;
    a0 = a0 >= 0.f ? a0 : 0.2f * a0;
    a1 = a1 >= 0.f ? a1 : 0.2f * a1;
    a2 = a2 >= 0.f ? a2 : 0.2f * a2;
    a3 = a3 >= 0.f ? a3 : 0.2f * a3;
    float* dp = denom + (size_t)d * 4;
    atomicAdd(dp + 0, __expf(a0));
    atomicAdd(dp + 1, __expf(a1));
    atomicAdd(dp + 2, __expf(a2));
    atomicAdd(dp + 3, __expf(a3));
}

// ---------------------------------------------------------------------------
// Kernel 4: aggregation. one thread per (edge, channel):
//   out[d, c] += exp(leaky(a_src[s,h]+a_dst[d,h]))/denom[d,h] * h[s, c]
// (recompute exp instead of storing E*H weights)
// ---------------------------------------------------------------------------
__global__ void k_aggr(const int* __restrict__ ei,
                       const float* __restrict__ asrc,
                       const float* __restrict__ adst,
                       const float* __restrict__ denom,
                       const unsigned short* __restrict__ hfeat,
                       float* __restrict__ outacc, int E)
{
    int t = blockIdx.x * blockDim.x + threadIdx.x;
    if (t >= E * D128) return;
    const int e = t >> 7, c = t & 127;
    const int s = ei[e], d = ei[E + e];
    const int h = c >> 5;
    float a = asrc[(size_t)s * 4 + h] + adst[(size_t)d * 4 + h];
    a = a >= 0.f ? a : 0.2f * a;
    const float coeff = __expf(a) / (denom[(size_t)d * 4 + h] + 1e-16f);
    const float val = coeff * b2f(hfeat[(size_t)s * D128 + c]);
    atomicAdd(outacc + (size_t)d * D128 + c, val);
}

// ---------------------------------------------------------------------------
// Kernel 5: out = leaky(acc + bias_g, 0.01) @ W2^T + b2   (fp32 out)
// ---------------------------------------------------------------------------
__global__ __launch_bounds__(256) void k_final(
    const float* __restrict__ accin,
    const float* __restrict__ bias_g,
    const unsigned short* __restrict__ W2b,
    const float* __restrict__ b2,
    float* __restrict__ out, int N)
{
    const int wave = threadIdx.x >> 6;
    const int lane = threadIdx.x & 63;
    const int lmod = lane & 15;
    const int ldiv = lane >> 4;
    const int rowBase = blockIdx.x * 128;
    const int kOff = ldiv * 8;

    f32x4 acc[2][8] = {};
    #pragma unroll
    for (int ks = 0; ks < 4; ++ks) {
        const int kb = ks * 32 + kOff;
        bf16x8 afr[2];
        #pragma unroll
        for (int rt = 0; rt < 2; ++rt) {
            int row = rowBase + wave * 32 + rt * 16 + lmod;
            row = min(row, N - 1);
            const float* p = accin + (size_t)row * D128 + kb;
            float4 f0 = *(const float4*)p;
            float4 f1 = *(const float4*)(p + 4);
            float tmp[8] = { f0.x, f0.y, f0.z, f0.w, f1.x, f1.y, f1.z, f1.w };
            union { bf16x8 v; unsigned short s[8]; } o;
            #pragma unroll
            for (int j = 0; j < 8; ++j) {
                float f = tmp[j] + bias_g[kb + j];
                f = f >= 0.f ? f : 0.01f * f;
                o.s[j] = f2b(f);
            }
            afr[rt] = o.v;
        }
        #pragma unroll
        for (int ct = 0; ct < 8; ++ct) {
            bf16x8 bfr = *(const bf16x8*)(W2b + (size_t)(ct * 16 + lmod) * D128 + kb);
            acc[0][ct] = mfma16(afr[0], bfr, acc[0][ct]);
            acc[1][ct] = mfma16(afr[1], bfr, acc[1][ct]);
        }
    }

    #pragma unroll
    for (int ct = 0; ct < 8; ++ct) {
        const int col = ct * 16 + lmod;
        const float bb = b2[col];
        #pragma unroll
        for (int rt = 0; rt < 2; ++rt)
            #pragma unroll
            for (int r = 0; r < 4; ++r) {
                int row = rowBase + wave * 32 + rt * 16 + ldiv * 4 + r;
                if (row < N) out[(size_t)row * D128 + col] = acc[rt][ct][r] + bb;
            }
    }
}

// ---------------------------------------------------------------------------
extern "C" void kernel_launch(void* const* d_in, const int* in_sizes, int n_in,
                              void* d_out, int out_size, void* d_ws, size_t ws_size,
                              hipStream_t stream)
{
    const float* x    = (const float*)d_in[0];
    const int*   ei   = (const int*)d_in[1];
    // d_in[2] edge_type: unused by forward
    const float* W1   = (const float*)d_in[3];
    const float* b1   = (const float*)d_in[4];
    const float* Wg   = (const float*)d_in[5];
    const float* atts = (const float*)d_in[6];
    const float* attd = (const float*)d_in[7];
    const float* bg   = (const float*)d_in[8];
    const float* W2   = (const float*)d_in[9];
    const float* b2   = (const float*)d_in[10];
    float* out = (float*)d_out;

    const int N = in_sizes[0] / D128;
    const int E = in_sizes[1] / 2;

    // workspace layout (all 16B aligned)
    char* ws = (char*)d_ws;
    unsigned short* wbf = (unsigned short*)ws;                // 3*16384 bf16 = 96KB
    size_t off = 3 * 16384 * 2;
    unsigned short* hfeat = (unsigned short*)(ws + off);      // N*128 bf16
    off += (size_t)N * D128 * 2;
    float* asrc = (float*)(ws + off); off += (size_t)N * 4 * 4;
    float* adst = (float*)(ws + off); off += (size_t)N * 4 * 4;
    size_t zero_off = off;
    float* denom = (float*)(ws + off); off += (size_t)N * 4 * 4;
    float* outacc = (float*)(ws + off); off += (size_t)N * D128 * 4;

    // zero denom + outacc (contiguous)
    hipMemsetAsync(ws + zero_off, 0, (size_t)N * 4 * 4 + (size_t)N * D128 * 4, stream);

    k_cvt<<<48, 256, 0, stream>>>(W1, Wg, W2, wbf);

    const int nb = (N + 127) / 128;
    k_fused_gemm2<<<nb, 256, 0, stream>>>(x, wbf, b1, wbf + 16384, hfeat, N);
    k_att<<<(N * 4 + 255) / 256, 256, 0, stream>>>(hfeat, atts, attd, asrc, adst, N);
    k_denom<<<(E + 255) / 256, 256, 0, stream>>>(ei, asrc, adst, denom, E);
    const long long total = (long long)E * D128;
    k_aggr<<<(unsigned)((total + 255) / 256), 256, 0, stream>>>(ei, asrc, adst, denom, hfeat, outacc, E);
    k_final<<<nb, 256, 0, stream>>>(outacc, bg, wbf + 32768, b2, out, N);
}

// Round 4
// 583.452 us; speedup vs baseline: 2.1391x; 2.1391x over previous
//
#include <hip/hip_runtime.h>
#include <hip/hip_bf16.h>

#define D128 128

typedef __attribute__((ext_vector_type(8))) short bf16x8;
typedef __attribute__((ext_vector_type(4))) float f32x4;

__device__ __forceinline__ float b2f(unsigned short u) {
    union { unsigned int i; float f; } z;
    z.i = ((unsigned int)u) << 16;
    return z.f;
}

__device__ __forceinline__ unsigned short f2b(float f) {
    union { float f; unsigned int i; } z;
    z.f = f;
    unsigned int r = z.i + 0x7FFFu + ((z.i >> 16) & 1u);  // round-to-nearest-even
    return (unsigned short)(r >> 16);
}

__device__ __forceinline__ f32x4 mfma16(bf16x8 a, bf16x8 b, f32x4 c) {
    return __builtin_amdgcn_mfma_f32_16x16x32_bf16(a, b, c, 0, 0, 0);
}

// ---------------------------------------------------------------------------
// Kernel 0: convert W1, Wg, W2 (fp32 128x128 each) to bf16 in workspace.
// ---------------------------------------------------------------------------
__global__ void k_cvt(const float* __restrict__ W1,
                      const float* __restrict__ Wg,
                      const float* __restrict__ W2,
                      unsigned short* __restrict__ wbf)
{
    int t = blockIdx.x * blockDim.x + threadIdx.x;
    if (t >= 12288) return;
    const int mat = t / 4096;
    const int idx = (t % 4096) * 4;
    const float* src = mat == 0 ? W1 : (mat == 1 ? Wg : W2);
    float4 f = *(const float4*)(src + idx);
    unsigned short* dst = wbf + mat * 16384 + idx;
    dst[0] = f2b(f.x); dst[1] = f2b(f.y); dst[2] = f2b(f.z); dst[3] = f2b(f.w);
}

// ---------------------------------------------------------------------------
// Kernel 1: fused  y1 = leaky(x,0.01) @ W1^T + b1 ;  h = y1 @ Wg^T
// ---------------------------------------------------------------------------
#define LDST 136  // 128 + 8 bf16 padding

__global__ __launch_bounds__(256) void k_fused_gemm2(
    const float* __restrict__ x,
    const unsigned short* __restrict__ W1b,
    const float* __restrict__ b1,
    const unsigned short* __restrict__ Wgb,
    unsigned short* __restrict__ hfeat, int N)
{
    __shared__ unsigned short ldsY[128 * LDST];
    const int wave = threadIdx.x >> 6;
    const int lane = threadIdx.x & 63;
    const int lmod = lane & 15;
    const int ldiv = lane >> 4;
    const int rowBase = blockIdx.x * 128;
    const int kOff = ldiv * 8;

    f32x4 acc[2][8] = {};
    #pragma unroll
    for (int ks = 0; ks < 4; ++ks) {
        const int kb = ks * 32 + kOff;
        bf16x8 afr[2];
        #pragma unroll
        for (int rt = 0; rt < 2; ++rt) {
            int row = rowBase + wave * 32 + rt * 16 + lmod;
            row = min(row, N - 1);
            const float* px = x + (size_t)row * D128 + kb;
            float4 f0 = *(const float4*)px;
            float4 f1 = *(const float4*)(px + 4);
            float tmp[8] = { f0.x, f0.y, f0.z, f0.w, f1.x, f1.y, f1.z, f1.w };
            union { bf16x8 v; unsigned short s[8]; } o;
            #pragma unroll
            for (int j = 0; j < 8; ++j) {
                float f = tmp[j];
                f = f >= 0.f ? f : 0.01f * f;
                o.s[j] = f2b(f);
            }
            afr[rt] = o.v;
        }
        #pragma unroll
        for (int ct = 0; ct < 8; ++ct) {
            bf16x8 bfr = *(const bf16x8*)(W1b + (size_t)(ct * 16 + lmod) * D128 + kb);
            acc[0][ct] = mfma16(afr[0], bfr, acc[0][ct]);
            acc[1][ct] = mfma16(afr[1], bfr, acc[1][ct]);
        }
    }

    #pragma unroll
    for (int ct = 0; ct < 8; ++ct) {
        const int col = ct * 16 + lmod;
        const float bias = b1[col];
        #pragma unroll
        for (int rt = 0; rt < 2; ++rt)
            #pragma unroll
            for (int r = 0; r < 4; ++r) {
                int rowl = wave * 32 + rt * 16 + ldiv * 4 + r;
                ldsY[rowl * LDST + col] = f2b(acc[rt][ct][r] + bias);
            }
    }
    __syncthreads();

    f32x4 acc2[2][8] = {};
    #pragma unroll
    for (int ks = 0; ks < 4; ++ks) {
        const int kb = ks * 32 + kOff;
        bf16x8 afr[2];
        #pragma unroll
        for (int rt = 0; rt < 2; ++rt) {
            int rowl = wave * 32 + rt * 16 + lmod;
            afr[rt] = *(const bf16x8*)&ldsY[rowl * LDST + kb];
        }
        #pragma unroll
        for (int ct = 0; ct < 8; ++ct) {
            bf16x8 bfr = *(const bf16x8*)(Wgb + (size_t)(ct * 16 + lmod) * D128 + kb);
            acc2[0][ct] = mfma16(afr[0], bfr, acc2[0][ct]);
            acc2[1][ct] = mfma16(afr[1], bfr, acc2[1][ct]);
        }
    }

    #pragma unroll
    for (int ct = 0; ct < 8; ++ct) {
        const int col = ct * 16 + lmod;
        #pragma unroll
        for (int rt = 0; rt < 2; ++rt)
            #pragma unroll
            for (int r = 0; r < 4; ++r) {
                int row = rowBase + wave * 32 + rt * 16 + ldiv * 4 + r;
                if (row < N) hfeat[(size_t)row * D128 + col] = f2b(acc2[rt][ct][r]);
            }
    }
}

// ---------------------------------------------------------------------------
// Kernel 2: a_src[n,h], a_dst[n,h] — one thread per (node, head)
// ---------------------------------------------------------------------------
__global__ void k_att(const unsigned short* __restrict__ hfeat,
                      const float* __restrict__ att_s,
                      const float* __restrict__ att_d,
                      float* __restrict__ asrc, float* __restrict__ adst, int N)
{
    int t = blockIdx.x * blockDim.x + threadIdx.x;
    if (t >= N * 4) return;
    const int node = t >> 2, head = t & 3;
    const unsigned short* p  = hfeat + (size_t)node * D128 + head * 32;
    const float* ps = att_s + head * 32;
    const float* pd = att_d + head * 32;
    float s = 0.f, d = 0.f;
    #pragma unroll
    for (int j0 = 0; j0 < 32; j0 += 8) {
        union { uint4 q; unsigned short s[8]; } u;
        u.q = *(const uint4*)(p + j0);
        #pragma unroll
        for (int j = 0; j < 8; ++j) {
            float f = b2f(u.s[j]);
            s += f * ps[j0 + j];
            d += f * pd[j0 + j];
        }
    }
    asrc[t] = s;
    adst[t] = d;
}

// ---------------------------------------------------------------------------
// CSR build: histogram -> 2-level exclusive scan -> bucket fill (stores src)
// ---------------------------------------------------------------------------
__global__ void k_hist(const int* __restrict__ ei, int* __restrict__ deg, int E)
{
    int e = blockIdx.x * blockDim.x + threadIdx.x;
    if (e >= E) return;
    atomicAdd(&deg[ei[E + e]], 1);
}

__global__ __launch_bounds__(1024) void k_scan1(
    const int* __restrict__ deg, int* __restrict__ scanned,
    int* __restrict__ bsum, int n)
{
    __shared__ int lds[1024];
    const int gid = blockIdx.x * 1024 + threadIdx.x;
    const int v = gid < n ? deg[gid] : 0;
    lds[threadIdx.x] = v;
    __syncthreads();
    #pragma unroll
    for (int off = 1; off < 1024; off <<= 1) {
        int t = threadIdx.x >= off ? lds[threadIdx.x - off] : 0;
        __syncthreads();
        lds[threadIdx.x] += t;
        __syncthreads();
    }
    if (gid < n) scanned[gid] = lds[threadIdx.x] - v;   // exclusive
    if (threadIdx.x == 1023) bsum[blockIdx.x] = lds[1023];
}

__global__ __launch_bounds__(1024) void k_scan2(int* __restrict__ bsum, int nb)
{
    __shared__ int lds[1024];
    const int v = threadIdx.x < nb ? bsum[threadIdx.x] : 0;
    lds[threadIdx.x] = v;
    __syncthreads();
    #pragma unroll
    for (int off = 1; off < 1024; off <<= 1) {
        int t = threadIdx.x >= off ? lds[threadIdx.x - off] : 0;
        __syncthreads();
        lds[threadIdx.x] += t;
        __syncthreads();
    }
    if (threadIdx.x < nb) bsum[threadIdx.x] = lds[threadIdx.x] - v;  // exclusive
}

__global__ void k_scan3(const int* __restrict__ scanned,
                        const int* __restrict__ bsum,
                        int* __restrict__ cursor, int n)
{
    int gid = blockIdx.x * blockDim.x + threadIdx.x;
    if (gid < n) cursor[gid] = scanned[gid] + bsum[gid >> 10];
}

__global__ void k_fill(const int* __restrict__ ei, int* __restrict__ cursor,
                       int* __restrict__ bucket, int E)
{
    int e = blockIdx.x * blockDim.x + threadIdx.x;
    if (e >= E) return;
    const int s = ei[e], d = ei[E + e];
    const int pos = atomicAdd(&cursor[d], 1);
    bucket[pos] = s;
}

// ---------------------------------------------------------------------------
// Kernel 4: GAT aggregation, gather-style. One wave per dst node.
// Lane handles channels {2*lane, 2*lane+1} (same head h=lane>>4).
// Fuses softmax denominator: out = sum(w*h[src]) / sum(w).
// After k_fill, cursor[d] == row_end; start = end - deg[d].
// ---------------------------------------------------------------------------
__global__ __launch_bounds__(256) void k_gat(
    const int* __restrict__ bucket, const int* __restrict__ cursor,
    const int* __restrict__ deg,
    const float* __restrict__ asrc, const float* __restrict__ adst,
    const unsigned short* __restrict__ hfeat,
    unsigned short* __restrict__ outbf, int N)
{
    const int wave = threadIdx.x >> 6;
    const int lane = threadIdx.x & 63;
    const int d = blockIdx.x * 4 + wave;
    if (d >= N) return;
    const int end = cursor[d];
    const int cnt = deg[d];
    const int start = end - cnt;
    const int h = lane >> 4;
    const float a_d = adst[(size_t)d * 4 + h];

    float acc0 = 0.f, acc1 = 0.f, denom = 0.f;
    for (int j = start; j < end; ++j) {
        const int s = bucket[j];                       // wave-broadcast load
        float a = asrc[(size_t)s * 4 + h] + a_d;
        a = a >= 0.f ? a : 0.2f * a;
        const float w = __expf(a);
        denom += w;
        const unsigned int hp = *(const unsigned int*)(hfeat + (size_t)s * D128 + 2 * lane);
        acc0 += w * b2f((unsigned short)(hp & 0xFFFFu));
        acc1 += w * b2f((unsigned short)(hp >> 16));
    }
    const float inv = 1.f / (denom + 1e-16f);
    const unsigned int o = ((unsigned int)f2b(acc1 * inv) << 16) | f2b(acc0 * inv);
    *(unsigned int*)(outbf + (size_t)d * D128 + 2 * lane) = o;
}

// ---------------------------------------------------------------------------
// Kernel 5: out = leaky(gatout + bias_g, 0.01) @ W2^T + b2   (fp32 out)
// gatout is bf16.
// ---------------------------------------------------------------------------
__global__ __launch_bounds__(256) void k_final(
    const unsigned short* __restrict__ gatbf,
    const float* __restrict__ bias_g,
    const unsigned short* __restrict__ W2b,
    const float* __restrict__ b2,
    float* __restrict__ out, int N)
{
    const int wave = threadIdx.x >> 6;
    const int lane = threadIdx.x & 63;
    const int lmod = lane & 15;
    const int ldiv = lane >> 4;
    const int rowBase = blockIdx.x * 128;
    const int kOff = ldiv * 8;

    f32x4 acc[2][8] = {};
    #pragma unroll
    for (int ks = 0; ks < 4; ++ks) {
        const int kb = ks * 32 + kOff;
        bf16x8 afr[2];
        #pragma unroll
        for (int rt = 0; rt < 2; ++rt) {
            int row = rowBase + wave * 32 + rt * 16 + lmod;
            row = min(row, N - 1);
            union { uint4 q; unsigned short s[8]; } u;
            u.q = *(const uint4*)(gatbf + (size_t)row * D128 + kb);
            union { bf16x8 v; unsigned short s[8]; } o;
            #pragma unroll
            for (int j = 0; j < 8; ++j) {
                float f = b2f(u.s[j]) + bias_g[kb + j];
                f = f >= 0.f ? f : 0.01f * f;
                o.s[j] = f2b(f);
            }
            afr[rt] = o.v;
        }
        #pragma unroll
        for (int ct = 0; ct < 8; ++ct) {
            bf16x8 bfr = *(const bf16x8*)(W2b + (size_t)(ct * 16 + lmod) * D128 + kb);
            acc[0][ct] = mfma16(afr[0], bfr, acc[0][ct]);
            acc[1][ct] = mfma16(afr[1], bfr, acc[1][ct]);
        }
    }

    #pragma unroll
    for (int ct = 0; ct < 8; ++ct) {
        const int col = ct * 16 + lmod;
        const float bb = b2[col];
        #pragma unroll
        for (int rt = 0; rt < 2; ++rt)
            #pragma unroll
            for (int r = 0; r < 4; ++r) {
                int row = rowBase + wave * 32 + rt * 16 + ldiv * 4 + r;
                if (row < N) out[(size_t)row * D128 + col] = acc[rt][ct][r] + bb;
            }
    }
}

// ---------------------------------------------------------------------------
extern "C" void kernel_launch(void* const* d_in, const int* in_sizes, int n_in,
                              void* d_out, int out_size, void* d_ws, size_t ws_size,
                              hipStream_t stream)
{
    const float* x    = (const float*)d_in[0];
    const int*   ei   = (const int*)d_in[1];
    // d_in[2] edge_type: unused by forward
    const float* W1   = (const float*)d_in[3];
    const float* b1   = (const float*)d_in[4];
    const float* Wg   = (const float*)d_in[5];
    const float* atts = (const float*)d_in[6];
    const float* attd = (const float*)d_in[7];
    const float* bg   = (const float*)d_in[8];
    const float* W2   = (const float*)d_in[9];
    const float* b2   = (const float*)d_in[10];
    float* out = (float*)d_out;

    const int N = in_sizes[0] / D128;
    const int E = in_sizes[1] / 2;

    // workspace layout (16B aligned pieces)
    char* ws = (char*)d_ws;
    unsigned short* wbf = (unsigned short*)ws;                 // 96 KB
    size_t off = 3 * 16384 * 2;
    unsigned short* hfeat = (unsigned short*)(ws + off); off += (size_t)N * D128 * 2;
    float* asrc = (float*)(ws + off); off += (size_t)N * 4 * 4;
    float* adst = (float*)(ws + off); off += (size_t)N * 4 * 4;
    int* deg     = (int*)(ws + off); off += (size_t)N * 4;     // memset to 0
    int* cursor  = (int*)(ws + off); off += (size_t)N * 4;
    int* scanned = (int*)(ws + off); off += (size_t)N * 4;
    int* bsum    = (int*)(ws + off); off += 1024 * 4;
    int* bucket  = (int*)(ws + off); off += (size_t)E * 4;
    unsigned short* outbf = (unsigned short*)(ws + off); off += (size_t)N * D128 * 2;

    hipMemsetAsync(deg, 0, (size_t)N * 4, stream);

    k_cvt<<<48, 256, 0, stream>>>(W1, Wg, W2, wbf);

    const int nb = (N + 127) / 128;
    k_fused_gemm2<<<nb, 256, 0, stream>>>(x, wbf, b1, wbf + 16384, hfeat, N);
    k_att<<<(N * 4 + 255) / 256, 256, 0, stream>>>(hfeat, atts, attd, asrc, adst, N);

    // CSR build
    k_hist<<<(E + 255) / 256, 256, 0, stream>>>(ei, deg, E);
    const int nb1 = (N + 1023) / 1024;
    k_scan1<<<nb1, 1024, 0, stream>>>(deg, scanned, bsum, N);
    k_scan2<<<1, 1024, 0, stream>>>(bsum, nb1);
    k_scan3<<<(N + 255) / 256, 256, 0, stream>>>(scanned, bsum, cursor, N);
    k_fill<<<(E + 255) / 256, 256, 0, stream>>>(ei, cursor, bucket, E);

    // gather-style GAT aggregation (fused softmax)
    k_gat<<<(N + 3) / 4, 256, 0, stream>>>(bucket, cursor, deg, asrc, adst,
                                           hfeat, outbf, N);

    k_final<<<nb, 256, 0, stream>>>(outbf, bg, wbf + 32768, b2, out, N);
}

// Round 5
// 485.166 us; speedup vs baseline: 2.5724x; 1.2026x over previous
//
#include <hip/hip_runtime.h>
#include <hip/hip_bf16.h>

#define D128 128

typedef __attribute__((ext_vector_type(8))) short bf16x8;
typedef __attribute__((ext_vector_type(4))) float f32x4;

__device__ __forceinline__ float b2f(unsigned short u) {
    union { unsigned int i; float f; } z;
    z.i = ((unsigned int)u) << 16;
    return z.f;
}

__device__ __forceinline__ unsigned short f2b(float f) {
    union { float f; unsigned int i; } z;
    z.f = f;
    unsigned int r = z.i + 0x7FFFu + ((z.i >> 16) & 1u);  // round-to-nearest-even
    return (unsigned short)(r >> 16);
}

__device__ __forceinline__ f32x4 mfma16(bf16x8 a, bf16x8 b, f32x4 c) {
    return __builtin_amdgcn_mfma_f32_16x16x32_bf16(a, b, c, 0, 0, 0);
}

// ---------------------------------------------------------------------------
// Kernel 0: convert W1, Wg, W2 (fp32 128x128 each) to bf16 in workspace.
// ---------------------------------------------------------------------------
__global__ void k_cvt(const float* __restrict__ W1,
                      const float* __restrict__ Wg,
                      const float* __restrict__ W2,
                      unsigned short* __restrict__ wbf)
{
    int t = blockIdx.x * blockDim.x + threadIdx.x;
    if (t >= 12288) return;
    const int mat = t / 4096;
    const int idx = (t % 4096) * 4;
    const float* src = mat == 0 ? W1 : (mat == 1 ? Wg : W2);
    float4 f = *(const float4*)(src + idx);
    unsigned short* dst = wbf + mat * 16384 + idx;
    dst[0] = f2b(f.x); dst[1] = f2b(f.y); dst[2] = f2b(f.z); dst[3] = f2b(f.w);
}

// ---------------------------------------------------------------------------
// Kernel 1: fused  y1 = leaky(x,0.01)@W1^T + b1 ; h = y1@Wg^T ; a_src/a_dst
// a_src/a_dst computed in-register from acc2 via 16-lane xor-shuffle reduce
// (replaces the former k_att kernel and its 25.6 MB re-read).
// ---------------------------------------------------------------------------
#define LDST 136  // 128 + 8 bf16 padding

__global__ __launch_bounds__(256) void k_fused_gemm2(
    const float* __restrict__ x,
    const unsigned short* __restrict__ W1b,
    const float* __restrict__ b1,
    const unsigned short* __restrict__ Wgb,
    const float* __restrict__ att_s,
    const float* __restrict__ att_d,
    unsigned short* __restrict__ hfeat,
    float* __restrict__ asrc, float* __restrict__ adst, int N)
{
    __shared__ unsigned short ldsY[128 * LDST];
    const int wave = threadIdx.x >> 6;
    const int lane = threadIdx.x & 63;
    const int lmod = lane & 15;
    const int ldiv = lane >> 4;
    const int rowBase = blockIdx.x * 128;
    const int kOff = ldiv * 8;

    // ---- GEMM1 ----
    f32x4 acc[2][8] = {};
    #pragma unroll
    for (int ks = 0; ks < 4; ++ks) {
        const int kb = ks * 32 + kOff;
        bf16x8 afr[2];
        #pragma unroll
        for (int rt = 0; rt < 2; ++rt) {
            int row = rowBase + wave * 32 + rt * 16 + lmod;
            row = min(row, N - 1);
            const float* px = x + (size_t)row * D128 + kb;
            float4 f0 = *(const float4*)px;
            float4 f1 = *(const float4*)(px + 4);
            float tmp[8] = { f0.x, f0.y, f0.z, f0.w, f1.x, f1.y, f1.z, f1.w };
            union { bf16x8 v; unsigned short s[8]; } o;
            #pragma unroll
            for (int j = 0; j < 8; ++j) {
                float f = tmp[j];
                f = f >= 0.f ? f : 0.01f * f;
                o.s[j] = f2b(f);
            }
            afr[rt] = o.v;
        }
        #pragma unroll
        for (int ct = 0; ct < 8; ++ct) {
            bf16x8 bfr = *(const bf16x8*)(W1b + (size_t)(ct * 16 + lmod) * D128 + kb);
            acc[0][ct] = mfma16(afr[0], bfr, acc[0][ct]);
            acc[1][ct] = mfma16(afr[1], bfr, acc[1][ct]);
        }
    }

    #pragma unroll
    for (int ct = 0; ct < 8; ++ct) {
        const int col = ct * 16 + lmod;
        const float bias = b1[col];
        #pragma unroll
        for (int rt = 0; rt < 2; ++rt)
            #pragma unroll
            for (int r = 0; r < 4; ++r) {
                int rowl = wave * 32 + rt * 16 + ldiv * 4 + r;
                ldsY[rowl * LDST + col] = f2b(acc[rt][ct][r] + bias);
            }
    }
    __syncthreads();

    // ---- GEMM2 ----
    f32x4 acc2[2][8] = {};
    #pragma unroll
    for (int ks = 0; ks < 4; ++ks) {
        const int kb = ks * 32 + kOff;
        bf16x8 afr[2];
        #pragma unroll
        for (int rt = 0; rt < 2; ++rt) {
            int rowl = wave * 32 + rt * 16 + lmod;
            afr[rt] = *(const bf16x8*)&ldsY[rowl * LDST + kb];
        }
        #pragma unroll
        for (int ct = 0; ct < 8; ++ct) {
            bf16x8 bfr = *(const bf16x8*)(Wgb + (size_t)(ct * 16 + lmod) * D128 + kb);
            acc2[0][ct] = mfma16(afr[0], bfr, acc2[0][ct]);
            acc2[1][ct] = mfma16(afr[1], bfr, acc2[1][ct]);
        }
    }

    // store h (bf16)
    #pragma unroll
    for (int ct = 0; ct < 8; ++ct) {
        const int col = ct * 16 + lmod;
        #pragma unroll
        for (int rt = 0; rt < 2; ++rt)
            #pragma unroll
            for (int r = 0; r < 4; ++r) {
                int row = rowBase + wave * 32 + rt * 16 + ldiv * 4 + r;
                if (row < N) hfeat[(size_t)row * D128 + col] = f2b(acc2[rt][ct][r]);
            }
    }

    // fused attention logits: per row, per head hh, sum over that head's cols
    float attS[8], attD[8];
    #pragma unroll
    for (int ct = 0; ct < 8; ++ct) {
        attS[ct] = att_s[ct * 16 + lmod];
        attD[ct] = att_d[ct * 16 + lmod];
    }
    #pragma unroll
    for (int rt = 0; rt < 2; ++rt) {
        #pragma unroll
        for (int r = 0; r < 4; ++r) {
            float ps[4] = {0.f, 0.f, 0.f, 0.f};
            float pd[4] = {0.f, 0.f, 0.f, 0.f};
            #pragma unroll
            for (int ct = 0; ct < 8; ++ct) {
                const float v = b2f(f2b(acc2[rt][ct][r]));   // bf16-rounded h
                const int hh = ct >> 1;
                ps[hh] += v * attS[ct];
                pd[hh] += v * attD[ct];
            }
            #pragma unroll
            for (int hh = 0; hh < 4; ++hh) {
                #pragma unroll
                for (int off = 1; off < 16; off <<= 1) {
                    ps[hh] += __shfl_xor(ps[hh], off);
                    pd[hh] += __shfl_xor(pd[hh], off);
                }
            }
            const int row = rowBase + wave * 32 + rt * 16 + ldiv * 4 + r;
            if (row < N) {
                if (lmod < 4)            asrc[(size_t)row * 4 + lmod]     = ps[lmod];
                else if (lmod < 8)       adst[(size_t)row * 4 + lmod - 4] = pd[lmod - 4];
            }
        }
    }
}

// ---------------------------------------------------------------------------
// CSR build: histogram -> 2-level exclusive scan -> bucket fill (stores src)
// ---------------------------------------------------------------------------
__global__ void k_hist(const int* __restrict__ ei, int* __restrict__ deg, int E)
{
    int e = blockIdx.x * blockDim.x + threadIdx.x;
    if (e >= E) return;
    atomicAdd(&deg[ei[E + e]], 1);
}

__global__ __launch_bounds__(1024) void k_scan1(
    const int* __restrict__ deg, int* __restrict__ scanned,
    int* __restrict__ bsum, int n)
{
    __shared__ int lds[1024];
    const int gid = blockIdx.x * 1024 + threadIdx.x;
    const int v = gid < n ? deg[gid] : 0;
    lds[threadIdx.x] = v;
    __syncthreads();
    #pragma unroll
    for (int off = 1; off < 1024; off <<= 1) {
        int t = threadIdx.x >= off ? lds[threadIdx.x - off] : 0;
        __syncthreads();
        lds[threadIdx.x] += t;
        __syncthreads();
    }
    if (gid < n) scanned[gid] = lds[threadIdx.x] - v;   // exclusive (local)
    if (threadIdx.x == 1023) bsum[blockIdx.x] = lds[1023];
}

__global__ __launch_bounds__(1024) void k_scan2(int* __restrict__ bsum, int nb)
{
    __shared__ int lds[1024];
    const int v = threadIdx.x < nb ? bsum[threadIdx.x] : 0;
    lds[threadIdx.x] = v;
    __syncthreads();
    #pragma unroll
    for (int off = 1; off < 1024; off <<= 1) {
        int t = threadIdx.x >= off ? lds[threadIdx.x - off] : 0;
        __syncthreads();
        lds[threadIdx.x] += t;
        __syncthreads();
    }
    if (threadIdx.x < nb) bsum[threadIdx.x] = lds[threadIdx.x] - v;  // exclusive
}

// fill: pos = (local excl scan, atomically bumped) + block offset
__global__ void k_fill(const int* __restrict__ ei, int* __restrict__ scanned,
                       const int* __restrict__ bsum,
                       int* __restrict__ bucket, int E)
{
    int e = blockIdx.x * blockDim.x + threadIdx.x;
    if (e >= E) return;
    const int s = ei[e], d = ei[E + e];
    const int pos = atomicAdd(&scanned[d], 1) + bsum[d >> 10];
    bucket[pos] = s;
}

// ---------------------------------------------------------------------------
// Kernel 4: GAT aggregation, gather-style, one wave per dst node.
// 4-way edge unroll: 4 independent 256B row gathers in flight per iteration.
// After k_fill: scanned[d] = local_excl + deg[d]  ->  end = scanned[d]+bsum.
// ---------------------------------------------------------------------------
__global__ __launch_bounds__(256) void k_gat(
    const int* __restrict__ bucket, const int* __restrict__ scanned,
    const int* __restrict__ bsum, const int* __restrict__ deg,
    const float* __restrict__ asrc, const float* __restrict__ adst,
    const unsigned short* __restrict__ hfeat,
    unsigned short* __restrict__ outbf, int N)
{
    const int wave = threadIdx.x >> 6;
    const int lane = threadIdx.x & 63;
    const int d = blockIdx.x * 4 + wave;
    if (d >= N) return;
    const int end = scanned[d] + bsum[d >> 10];
    const int cnt = deg[d];
    const int start = end - cnt;
    const int h = lane >> 4;
    const float a_d = adst[(size_t)d * 4 + h];

    float acc0 = 0.f, acc1 = 0.f, denom = 0.f;
    int j = start;
    for (; j + 4 <= end; j += 4) {
        const int s0 = bucket[j];
        const int s1 = bucket[j + 1];
        const int s2 = bucket[j + 2];
        const int s3 = bucket[j + 3];
        const float as0 = asrc[(size_t)s0 * 4 + h];
        const float as1 = asrc[(size_t)s1 * 4 + h];
        const float as2 = asrc[(size_t)s2 * 4 + h];
        const float as3 = asrc[(size_t)s3 * 4 + h];
        const unsigned int hp0 = *(const unsigned int*)(hfeat + (size_t)s0 * D128 + 2 * lane);
        const unsigned int hp1 = *(const unsigned int*)(hfeat + (size_t)s1 * D128 + 2 * lane);
        const unsigned int hp2 = *(const unsigned int*)(hfeat + (size_t)s2 * D128 + 2 * lane);
        const unsigned int hp3 = *(const unsigned int*)(hfeat + (size_t)s3 * D128 + 2 * lane);
        float a0 = as0 + a_d; a0 = a0 >= 0.f ? a0 : 0.2f * a0;
        float a1 = as1 + a_d; a1 = a1 >= 0.f ? a1 : 0.2f * a1;
        float a2 = as2 + a_d; a2 = a2 >= 0.f ? a2 : 0.2f * a2;
        float a3 = as3 + a_d; a3 = a3 >= 0.f ? a3 : 0.2f * a3;
        const float w0 = __expf(a0), w1 = __expf(a1), w2 = __expf(a2), w3 = __expf(a3);
        denom += (w0 + w1) + (w2 + w3);
        acc0 += w0 * b2f((unsigned short)(hp0 & 0xFFFFu))
              + w1 * b2f((unsigned short)(hp1 & 0xFFFFu))
              + w2 * b2f((unsigned short)(hp2 & 0xFFFFu))
              + w3 * b2f((unsigned short)(hp3 & 0xFFFFu));
        acc1 += w0 * b2f((unsigned short)(hp0 >> 16))
              + w1 * b2f((unsigned short)(hp1 >> 16))
              + w2 * b2f((unsigned short)(hp2 >> 16))
              + w3 * b2f((unsigned short)(hp3 >> 16));
    }
    for (; j < end; ++j) {
        const int s = bucket[j];
        float a = asrc[(size_t)s * 4 + h] + a_d;
        a = a >= 0.f ? a : 0.2f * a;
        const float w = __expf(a);
        denom += w;
        const unsigned int hp = *(const unsigned int*)(hfeat + (size_t)s * D128 + 2 * lane);
        acc0 += w * b2f((unsigned short)(hp & 0xFFFFu));
        acc1 += w * b2f((unsigned short)(hp >> 16));
    }
    const float inv = 1.f / (denom + 1e-16f);
    const unsigned int o = ((unsigned int)f2b(acc1 * inv) << 16) | f2b(acc0 * inv);
    *(unsigned int*)(outbf + (size_t)d * D128 + 2 * lane) = o;
}

// ---------------------------------------------------------------------------
// Kernel 5: out = leaky(gatout + bias_g, 0.01) @ W2^T + b2   (fp32 out)
// ---------------------------------------------------------------------------
__global__ __launch_bounds__(256) void k_final(
    const unsigned short* __restrict__ gatbf,
    const float* __restrict__ bias_g,
    const unsigned short* __restrict__ W2b,
    const float* __restrict__ b2,
    float* __restrict__ out, int N)
{
    const int wave = threadIdx.x >> 6;
    const int lane = threadIdx.x & 63;
    const int lmod = lane & 15;
    const int ldiv = lane >> 4;
    const int rowBase = blockIdx.x * 128;
    const int kOff = ldiv * 8;

    f32x4 acc[2][8] = {};
    #pragma unroll
    for (int ks = 0; ks < 4; ++ks) {
        const int kb = ks * 32 + kOff;
        bf16x8 afr[2];
        #pragma unroll
        for (int rt = 0; rt < 2; ++rt) {
            int row = rowBase + wave * 32 + rt * 16 + lmod;
            row = min(row, N - 1);
            union { uint4 q; unsigned short s[8]; } u;
            u.q = *(const uint4*)(gatbf + (size_t)row * D128 + kb);
            union { bf16x8 v; unsigned short s[8]; } o;
            #pragma unroll
            for (int j = 0; j < 8; ++j) {
                float f = b2f(u.s[j]) + bias_g[kb + j];
                f = f >= 0.f ? f : 0.01f * f;
                o.s[j] = f2b(f);
            }
            afr[rt] = o.v;
        }
        #pragma unroll
        for (int ct = 0; ct < 8; ++ct) {
            bf16x8 bfr = *(const bf16x8*)(W2b + (size_t)(ct * 16 + lmod) * D128 + kb);
            acc[0][ct] = mfma16(afr[0], bfr, acc[0][ct]);
            acc[1][ct] = mfma16(afr[1], bfr, acc[1][ct]);
        }
    }

    #pragma unroll
    for (int ct = 0; ct < 8; ++ct) {
        const int col = ct * 16 + lmod;
        const float bb = b2[col];
        #pragma unroll
        for (int rt = 0; rt < 2; ++rt)
            #pragma unroll
            for (int r = 0; r < 4; ++r) {
                int row = rowBase + wave * 32 + rt * 16 + ldiv * 4 + r;
                if (row < N) out[(size_t)row * D128 + col] = acc[rt][ct][r] + bb;
            }
    }
}

// ---------------------------------------------------------------------------
extern "C" void kernel_launch(void* const* d_in, const int* in_sizes, int n_in,
                              void* d_out, int out_size, void* d_ws, size_t ws_size,
                              hipStream_t stream)
{
    const float* x    = (const float*)d_in[0];
    const int*   ei   = (const int*)d_in[1];
    // d_in[2] edge_type: unused by forward
    const float* W1   = (const float*)d_in[3];
    const float* b1   = (const float*)d_in[4];
    const float* Wg   = (const float*)d_in[5];
    const float* atts = (const float*)d_in[6];
    const float* attd = (const float*)d_in[7];
    const float* bg   = (const float*)d_in[8];
    const float* W2   = (const float*)d_in[9];
    const float* b2   = (const float*)d_in[10];
    float* out = (float*)d_out;

    const int N = in_sizes[0] / D128;
    const int E = in_sizes[1] / 2;

    // workspace layout (16B aligned pieces)
    char* ws = (char*)d_ws;
    unsigned short* wbf = (unsigned short*)ws;                 // 96 KB
    size_t off = 3 * 16384 * 2;
    unsigned short* hfeat = (unsigned short*)(ws + off); off += (size_t)N * D128 * 2;
    float* asrc = (float*)(ws + off); off += (size_t)N * 4 * 4;
    float* adst = (float*)(ws + off); off += (size_t)N * 4 * 4;
    int* deg     = (int*)(ws + off); off += (size_t)N * 4;     // memset to 0
    int* scanned = (int*)(ws + off); off += (size_t)N * 4;
    int* bsum    = (int*)(ws + off); off += 1024 * 4;
    int* bucket  = (int*)(ws + off); off += (size_t)E * 4;
    unsigned short* outbf = (unsigned short*)(ws + off); off += (size_t)N * D128 * 2;

    hipMemsetAsync(deg, 0, (size_t)N * 4, stream);

    k_cvt<<<48, 256, 0, stream>>>(W1, Wg, W2, wbf);

    const int nb = (N + 127) / 128;
    k_fused_gemm2<<<nb, 256, 0, stream>>>(x, wbf, b1, wbf + 16384, atts, attd,
                                          hfeat, asrc, adst, N);

    // CSR build
    k_hist<<<(E + 255) / 256, 256, 0, stream>>>(ei, deg, E);
    const int nb1 = (N + 1023) / 1024;
    k_scan1<<<nb1, 1024, 0, stream>>>(deg, scanned, bsum, N);
    k_scan2<<<1, 1024, 0, stream>>>(bsum, nb1);
    k_fill<<<(E + 255) / 256, 256, 0, stream>>>(ei, scanned, bsum, bucket, E);

    // gather-style GAT aggregation (fused softmax), 4-way edge unroll
    k_gat<<<(N + 3) / 4, 256, 0, stream>>>(bucket, scanned, bsum, deg,
                                           asrc, adst, hfeat, outbf, N);

    k_final<<<nb, 256, 0, stream>>>(outbf, bg, wbf + 32768, b2, out, N);
}